// Round 1
// baseline (1128.629 us; speedup 1.0000x reference)
//
#include <hip/hip_runtime.h>

// Problem constants (fixed by reference): B=4, C=64, H=W=64 -> N=4096
#define NN 4096
#define CD 64
#define NB 4

// Device-global workspace (avoids any assumption about ws_size).
// ~34 MB total; fully rewritten every kernel_launch call.
__device__ float g_Q[2][NB][CD][NN];
__device__ float g_K[2][NB][CD][NN];
__device__ float g_V[2][NB][CD][NN];   // after scalev: V * g / Z  (row-i normalized)
__device__ float g_Obr[2][NB][CD][NN]; // per-branch attention outputs
__device__ float g_Z[2][NB][NN];       // softmax denominators per score-row i

struct ProjArgs {
  const float* x;
  const float* W[6];
  const float* bias[6];
};

// ---------------------------------------------------------------------------
// Kernel 1: all six 1x1-conv projections. q[b,o,n] = sum_c W[o,c] x[b,c,n] + b[o]
// grid (N/64, B, 6), block 256. W staged transposed+padded in LDS so the
// 16 weights per (c, o-group) come as 4 broadcast ds_read_b128.
// ---------------------------------------------------------------------------
__global__ __launch_bounds__(256) void proj_kernel(ProjArgs a) {
  __shared__ float Wt[64][68]; // transposed W: Wt[c][o]; +4 pad keeps 16B align
  __shared__ float bs[64];
  const int tid = threadIdx.x;
  const int m = blockIdx.z; // 0..5 = qh,kh,vh,ql,kl,vl
  const float* __restrict__ W = a.W[m];
#pragma unroll
  for (int k = 0; k < 16; ++k) {
    int t = k * 256 + tid;        // t = o*64 + c
    Wt[t & 63][t >> 6] = W[t];
  }
  if (tid < 64) bs[tid] = a.bias[m][tid];
  __syncthreads();

  const int b = blockIdx.y;
  const int n = (blockIdx.x << 6) + (tid & 63);
  const int og = tid >> 6; // o-group: o = og*16 .. +15 (wave-uniform)
  const float* __restrict__ xp = a.x + ((size_t)b * CD) * NN + n;

  float acc[16];
#pragma unroll
  for (int k = 0; k < 16; ++k) acc[k] = bs[og * 16 + k];

#pragma unroll 4
  for (int c = 0; c < 64; ++c) {
    float xv = xp[(size_t)c * NN];
    float w[16];
    *(float4*)&w[0]  = *(const float4*)&Wt[c][og * 16 + 0];
    *(float4*)&w[4]  = *(const float4*)&Wt[c][og * 16 + 4];
    *(float4*)&w[8]  = *(const float4*)&Wt[c][og * 16 + 8];
    *(float4*)&w[12] = *(const float4*)&Wt[c][og * 16 + 12];
#pragma unroll
    for (int k = 0; k < 16; ++k) acc[k] += w[k] * xv;
  }

  const int br = m / 3, kind = m % 3;
  float* base = (kind == 0) ? &g_Q[0][0][0][0]
              : (kind == 1) ? &g_K[0][0][0][0]
                            : &g_V[0][0][0][0];
  float* dst = base + (((size_t)br * NB + b) * CD) * NN + n;
#pragma unroll
  for (int k = 0; k < 16; ++k) dst[(size_t)(og * 16 + k) * NN] = acc[k];
}

// ---------------------------------------------------------------------------
// Kernel 2: pass 1 — Z[i] = sum_j exp(S[i,j]), S = Q^T K (K-dim = 64).
// grid (N/128, B, 2), block 256. Block owns 128 i-rows, iterates 64-wide
// j-tiles. 8x4 micro-tile per thread; z partials per thread, butterfly over
// the 16 tx lanes at the end. No max-subtraction (scores bounded ~±50).
// ---------------------------------------------------------------------------
__global__ __launch_bounds__(256) void pass1_kernel() {
  __shared__ float qs[64][128]; // [c][i]  32 KiB
  __shared__ float ks[64][64];  // [c][j]  16 KiB
  const int tid = threadIdx.x;
  const int br = blockIdx.z, b = blockIdx.y;
  const int i0 = blockIdx.x << 7;
  const float* __restrict__ Qb = &g_Q[br][b][0][0];
  const float* __restrict__ Kb = &g_K[br][b][0][0];

#pragma unroll
  for (int k = 0; k < 8; ++k) { // stage q panel once
    int t = k * 256 + tid;
    int c = t >> 5, col = t & 31;
    *(float4*)&qs[c][col * 4] = *(const float4*)&Qb[(size_t)c * NN + i0 + col * 4];
  }

  float4 pk[4]; // register prefetch of next k tile (T14 async-split)
#pragma unroll
  for (int k = 0; k < 4; ++k) {
    int t = k * 256 + tid;
    int c = t >> 4, col = t & 15;
    pk[k] = *(const float4*)&Kb[(size_t)c * NN + col * 4];
  }

  const int tx = tid & 15;  // j-group (4 j)
  const int ty = tid >> 4;  // i-group (8 i), 16 groups
  const int ty8 = ty * 8, tx4 = tx * 4;
  float zacc[8];
#pragma unroll
  for (int r = 0; r < 8; ++r) zacc[r] = 0.f;

  for (int jt = 0; jt < 64; ++jt) {
#pragma unroll
    for (int k = 0; k < 4; ++k) { // commit prefetched k tile to LDS
      int t = k * 256 + tid;
      int c = t >> 4, col = t & 15;
      *(float4*)&ks[c][col * 4] = pk[k];
    }
    __syncthreads(); // ks (and first-iter qs) visible
    if (jt < 63) {
#pragma unroll
      for (int k = 0; k < 4; ++k) { // issue next tile's global loads now
        int t = k * 256 + tid;
        int c = t >> 4, col = t & 15;
        pk[k] = *(const float4*)&Kb[(size_t)c * NN + ((jt + 1) << 6) + col * 4];
      }
    }

    float acc[8][4];
#pragma unroll
    for (int r = 0; r < 8; ++r)
#pragma unroll
      for (int j = 0; j < 4; ++j) acc[r][j] = 0.f;

#pragma unroll 4
    for (int c = 0; c < 64; ++c) {
      float qv[8], kv[4];
      *(float4*)&qv[0] = *(const float4*)&qs[c][ty8];     // broadcast reads
      *(float4*)&qv[4] = *(const float4*)&qs[c][ty8 + 4];
      *(float4*)&kv[0] = *(const float4*)&ks[c][tx4];     // 256B contiguous
#pragma unroll
      for (int r = 0; r < 8; ++r)
#pragma unroll
        for (int j = 0; j < 4; ++j) acc[r][j] += qv[r] * kv[j];
    }
#pragma unroll
    for (int r = 0; r < 8; ++r)
      zacc[r] += __expf(acc[r][0]) + __expf(acc[r][1]) +
                 __expf(acc[r][2]) + __expf(acc[r][3]);
    __syncthreads(); // compute done before next ks overwrite
  }

#pragma unroll
  for (int mm = 1; mm < 16; mm <<= 1)
#pragma unroll
    for (int r = 0; r < 8; ++r) zacc[r] += __shfl_xor(zacc[r], mm, 64);

  if (tx == 0) {
#pragma unroll
    for (int r = 0; r < 8; ++r) g_Z[br][b][i0 + ty8 + r] = zacc[r];
  }
}

// ---------------------------------------------------------------------------
// Kernel 3: fold g / Z into V:  V[br,b,c,i] *= g_br / Z[br,b,i]
// ---------------------------------------------------------------------------
__global__ __launch_bounds__(256) void scalev_kernel(const float* __restrict__ g1,
                                                     const float* __restrict__ g2) {
  int idx = blockIdx.x * 256 + threadIdx.x; // over 2*4*64*1024 float4 chunks
  int i4 = idx & 1023;
  int c  = (idx >> 10) & 63;
  int b  = (idx >> 16) & 3;
  int br = idx >> 18;
  float g = br ? g2[0] : g1[0];
  const float4 z = *(const float4*)&g_Z[br][b][i4 * 4];
  float4 v = *(float4*)&g_V[br][b][c][i4 * 4];
  v.x *= g / z.x;
  v.y *= g / z.y;
  v.z *= g / z.z;
  v.w *= g / z.w;
  *(float4*)&g_V[br][b][c][i4 * 4] = v;
}

// ---------------------------------------------------------------------------
// Kernel 4: pass 2 — O[c,j] = sum_i Vn[c,i] * exp(S[i,j]).
// grid (N/128, B, 2), block 256. Block owns O[64c x 128j], iterates 64-wide
// i-tiles. Per tile: S (8x4 micro) -> P=exp(S) staged through LDS ->
// O += Vn x P (8x4 micro). q/v double-buffered; next tile prefetched into
// registers under the S matmul. 128 KiB dynamic LDS, 2 barriers/tile.
// ---------------------------------------------------------------------------
__global__ __launch_bounds__(256) void pass2_kernel() {
  extern __shared__ float smem[];
  float* ks  = smem;          // [64][128] k panel for this j-block (static)
  float* qsA = smem + 8192;   // [64][64]
  float* qsB = qsA + 4096;
  float* vsA = qsB + 4096;
  float* vsB = vsA + 4096;
  float* ps  = vsA + 8192;    // [64][128] P tile

  const int tid = threadIdx.x;
  const int br = blockIdx.z, b = blockIdx.y;
  const int j0 = blockIdx.x << 7;
  const float* __restrict__ Qb = &g_Q[br][b][0][0];
  const float* __restrict__ Kb = &g_K[br][b][0][0];
  const float* __restrict__ Vb = &g_V[br][b][0][0];

#pragma unroll
  for (int k = 0; k < 8; ++k) { // k panel, staged once
    int t = k * 256 + tid;
    int c = t >> 5, col = t & 31;
    *(float4*)&ks[c * 128 + col * 4] = *(const float4*)&Kb[(size_t)c * NN + j0 + col * 4];
  }
#pragma unroll
  for (int k = 0; k < 4; ++k) { // tile 0 q/v
    int t = k * 256 + tid;
    int c = t >> 4, col = t & 15;
    *(float4*)&qsA[c * 64 + col * 4] = *(const float4*)&Qb[(size_t)c * NN + col * 4];
    *(float4*)&vsA[c * 64 + col * 4] = *(const float4*)&Vb[(size_t)c * NN + col * 4];
  }
  __syncthreads();

  const int tx = tid & 31; // j-group (4 j)
  const int ty = tid >> 5; // 8 groups (rows for S, channels for O)
  const int ty8 = ty * 8, tx4 = tx * 4;

  float oacc[8][4];
#pragma unroll
  for (int r = 0; r < 8; ++r)
#pragma unroll
    for (int j = 0; j < 4; ++j) oacc[r][j] = 0.f;

  for (int t = 0; t < 64; ++t) {
    float* qc = (t & 1) ? qsB : qsA;
    float* vc = (t & 1) ? vsB : vsA;
    float* qn = (t & 1) ? qsA : qsB;
    float* vn = (t & 1) ? vsA : vsB;

    float4 pq[4], pv[4];
    if (t < 63) { // issue next tile's global loads; they complete under S
      const int i0n = (t + 1) << 6;
#pragma unroll
      for (int k = 0; k < 4; ++k) {
        int tt = k * 256 + tid;
        int c = tt >> 4, col = tt & 15;
        pq[k] = *(const float4*)&Qb[(size_t)c * NN + i0n + col * 4];
        pv[k] = *(const float4*)&Vb[(size_t)c * NN + i0n + col * 4];
      }
    }

    float acc[8][4];
#pragma unroll
    for (int r = 0; r < 8; ++r)
#pragma unroll
      for (int j = 0; j < 4; ++j) acc[r][j] = 0.f;

#pragma unroll 4
    for (int c = 0; c < 64; ++c) { // S = q^T k over 64 channels
      float qv[8], kv[4];
      *(float4*)&qv[0] = *(const float4*)&qc[c * 64 + ty8];
      *(float4*)&qv[4] = *(const float4*)&qc[c * 64 + ty8 + 4];
      *(float4*)&kv[0] = *(const float4*)&ks[c * 128 + tx4];
#pragma unroll
      for (int r = 0; r < 8; ++r)
#pragma unroll
        for (int j = 0; j < 4; ++j) acc[r][j] += qv[r] * kv[j];
    }

#pragma unroll
    for (int r = 0; r < 8; ++r) { // P = exp(S) -> LDS
      float4 p;
      p.x = __expf(acc[r][0]);
      p.y = __expf(acc[r][1]);
      p.z = __expf(acc[r][2]);
      p.w = __expf(acc[r][3]);
      *(float4*)&ps[(ty8 + r) * 128 + tx4] = p;
    }

    if (t < 63) { // commit prefetched q/v into the other buffer
#pragma unroll
      for (int k = 0; k < 4; ++k) {
        int tt = k * 256 + tid;
        int c = tt >> 4, col = tt & 15;
        *(float4*)&qn[c * 64 + col * 4] = pq[k];
        *(float4*)&vn[c * 64 + col * 4] = pv[k];
      }
    }
    __syncthreads(); // B: ps + staged next tile visible

#pragma unroll 2
    for (int ib = 0; ib < 16; ++ib) { // O += Vn x P over this tile's 64 i
      float vv[8][4];
#pragma unroll
      for (int cc = 0; cc < 8; ++cc)
        *(float4*)&vv[cc][0] = *(const float4*)&vc[(ty8 + cc) * 64 + ib * 4];
#pragma unroll
      for (int ii = 0; ii < 4; ++ii) {
        float pp[4];
        *(float4*)&pp[0] = *(const float4*)&ps[(ib * 4 + ii) * 128 + tx4];
#pragma unroll
        for (int cc = 0; cc < 8; ++cc)
#pragma unroll
          for (int j = 0; j < 4; ++j)
            oacc[cc][j] += vv[cc][ii] * pp[j];
      }
    }
    __syncthreads(); // C: ps/vc reads done before next tile writes
  }

  float* Ob = &g_Obr[br][b][0][0];
#pragma unroll
  for (int cc = 0; cc < 8; ++cc) {
    float4 o;
    o.x = oacc[cc][0]; o.y = oacc[cc][1]; o.z = oacc[cc][2]; o.w = oacc[cc][3];
    *(float4*)&Ob[(size_t)(ty8 + cc) * NN + j0 + tx4] = o;
  }
}

// ---------------------------------------------------------------------------
// Kernel 5: final 1x1 conv over concat: out[b,o,n] = b_f[o]
//   + sum_c Oh[b,c,n] Wf[o,c] + sum_c Ol[b,c,n] Wf[o,64+c]
// (g1/g2 already folded into V by scalev_kernel.)
// ---------------------------------------------------------------------------
__global__ __launch_bounds__(256) void final_kernel(const float* __restrict__ Wf,
                                                    const float* __restrict__ bf,
                                                    float* __restrict__ out) {
  __shared__ float Wt[128][68]; // transposed Wf: Wt[c'][o]
  __shared__ float bs[64];
  const int tid = threadIdx.x;
#pragma unroll
  for (int k = 0; k < 32; ++k) {
    int t = k * 256 + tid; // t = o*128 + c'
    Wt[t & 127][t >> 7] = Wf[t];
  }
  if (tid < 64) bs[tid] = bf[tid];
  __syncthreads();

  const int b = blockIdx.y;
  const int n = (blockIdx.x << 6) + (tid & 63);
  const int og = tid >> 6;
  const float* __restrict__ Oh = &g_Obr[0][b][0][0];
  const float* __restrict__ Ol = &g_Obr[1][b][0][0];

  float acc[16];
#pragma unroll
  for (int k = 0; k < 16; ++k) acc[k] = bs[og * 16 + k];

#pragma unroll 4
  for (int c = 0; c < 64; ++c) {
    float xv = Oh[(size_t)c * NN + n];
    float w[16];
    *(float4*)&w[0]  = *(const float4*)&Wt[c][og * 16 + 0];
    *(float4*)&w[4]  = *(const float4*)&Wt[c][og * 16 + 4];
    *(float4*)&w[8]  = *(const float4*)&Wt[c][og * 16 + 8];
    *(float4*)&w[12] = *(const float4*)&Wt[c][og * 16 + 12];
#pragma unroll
    for (int k = 0; k < 16; ++k) acc[k] += w[k] * xv;
  }
#pragma unroll 4
  for (int c = 0; c < 64; ++c) {
    float xv = Ol[(size_t)c * NN + n];
    float w[16];
    *(float4*)&w[0]  = *(const float4*)&Wt[64 + c][og * 16 + 0];
    *(float4*)&w[4]  = *(const float4*)&Wt[64 + c][og * 16 + 4];
    *(float4*)&w[8]  = *(const float4*)&Wt[64 + c][og * 16 + 8];
    *(float4*)&w[12] = *(const float4*)&Wt[64 + c][og * 16 + 12];
#pragma unroll
    for (int k = 0; k < 16; ++k) acc[k] += w[k] * xv;
  }

  float* op = out + ((size_t)b * CD) * NN + n;
#pragma unroll
  for (int k = 0; k < 16; ++k) op[(size_t)(og * 16 + k) * NN] = acc[k];
}

// ---------------------------------------------------------------------------
extern "C" void kernel_launch(void* const* d_in, const int* in_sizes, int n_in,
                              void* d_out, int out_size, void* d_ws, size_t ws_size,
                              hipStream_t stream) {
  (void)in_sizes; (void)n_in; (void)d_ws; (void)ws_size; (void)out_size;

  ProjArgs pa;
  pa.x = (const float*)d_in[0];
  for (int m = 0; m < 6; ++m) {
    pa.W[m]    = (const float*)d_in[1 + 2 * m]; // W_qh,W_kh,W_vh,W_ql,W_kl,W_vl
    pa.bias[m] = (const float*)d_in[2 + 2 * m];
  }
  const float* g1 = (const float*)d_in[13];
  const float* g2 = (const float*)d_in[14];
  const float* Wf = (const float*)d_in[15];
  const float* bf = (const float*)d_in[16];
  float* out = (float*)d_out;

  proj_kernel<<<dim3(64, 4, 6), 256, 0, stream>>>(pa);
  pass1_kernel<<<dim3(32, 4, 2), 256, 0, stream>>>();
  scalev_kernel<<<dim3(2048, 1, 1), 256, 0, stream>>>(g1, g2);
  // 128 KiB dynamic LDS (gfx950 allows up to 160 KiB); set attr idempotently.
  (void)hipFuncSetAttribute(reinterpret_cast<const void*>(pass2_kernel),
                            hipFuncAttributeMaxDynamicSharedMemorySize, 131072);
  pass2_kernel<<<dim3(32, 4, 2), 256, 131072, stream>>>();
  final_kernel<<<dim3(64, 4, 1), 256, 0, stream>>>(Wf, bf, out);
}

// Round 2
// 401.591 us; speedup vs baseline: 2.8104x; 2.8104x over previous
//
#include <hip/hip_runtime.h>

// Problem constants (fixed by reference): B=4, C=64, H=W=64 -> N=4096
#define NN 4096
#define CD 64

typedef __attribute__((ext_vector_type(8))) short bf16x8; // 8 bf16 in 4 VGPRs
typedef __attribute__((ext_vector_type(4))) float f32x4;

// Device-global workspace (~40 MB), fully rewritten each launch.
__device__ unsigned short g_Qh[2][4][NN][CD]; // Q^T hi  [n][c], c contiguous
__device__ unsigned short g_Ql[2][4][NN][CD]; // Q^T lo
__device__ unsigned short g_Kh[2][4][NN][CD]; // K^T hi
__device__ unsigned short g_Kl[2][4][NN][CD]; // K^T lo
__device__ float          g_Vf[2][4][CD][NN]; // V fp32 (pre-fold)
__device__ unsigned short g_Vh[2][4][CD][NN]; // V*g/Z hi
__device__ unsigned short g_Vl[2][4][CD][NN]; // V*g/Z lo
__device__ float          g_O [2][4][CD][NN]; // per-branch attn out (fp32)
__device__ float          g_Z [2][4][NN];     // softmax denominators

__device__ inline f32x4 mfma16(bf16x8 a, bf16x8 b, f32x4 c) {
  return __builtin_amdgcn_mfma_f32_16x16x32_bf16(a, b, c, 0, 0, 0);
}

// Truncation hi + RNE lo split: x ~= hi + lo, |x-(hi+lo)| <= 2^-17 |x|
__device__ inline void split_bf(float x, unsigned short& h, unsigned short& l) {
  unsigned u = __builtin_bit_cast(unsigned, x);
  h = (unsigned short)(u >> 16);
  float hf = __builtin_bit_cast(float, u & 0xffff0000u);
  unsigned v = __builtin_bit_cast(unsigned, x - hf);
  v += 0x7fffu + ((v >> 16) & 1u);
  l = (unsigned short)(v >> 16);
}

// Raw barrier: drain LDS ops only; global prefetches stay in flight (T4).
__device__ inline void lds_barrier() {
  asm volatile("s_waitcnt lgkmcnt(0)\n\ts_barrier" ::: "memory");
}

struct ProjArgs {
  const float* x;
  const float* W[6];
  const float* bias[6];
};

// ---------------------------------------------------------------------------
// Kernel 1: six 1x1-conv projections, fp32 compute.
// Q/K written transposed ([n][c], c contiguous) split into bf16 hi/lo.
// V written fp32 [c][n] (hi/lo split happens after the 1/Z fold).
// ---------------------------------------------------------------------------
__global__ __launch_bounds__(256) void proj_kernel(ProjArgs a) {
  __shared__ float Wt[64][68];
  __shared__ float bs[64];
  const int tid = threadIdx.x;
  const int m = blockIdx.z; // 0..5 = qh,kh,vh,ql,kl,vl
  const float* __restrict__ W = a.W[m];
#pragma unroll
  for (int k = 0; k < 16; ++k) {
    int t = k * 256 + tid; // t = o*64 + c
    Wt[t & 63][t >> 6] = W[t];
  }
  if (tid < 64) bs[tid] = a.bias[m][tid];
  __syncthreads();

  const int b = blockIdx.y;
  const int n = (blockIdx.x << 6) + (tid & 63);
  const int og = tid >> 6;
  const float* __restrict__ xp = a.x + ((size_t)b * CD) * NN + n;

  float acc[16];
#pragma unroll
  for (int k = 0; k < 16; ++k) acc[k] = bs[og * 16 + k];

#pragma unroll 4
  for (int c = 0; c < 64; ++c) {
    float xv = xp[(size_t)c * NN];
    float w[16];
    *(float4*)&w[0]  = *(const float4*)&Wt[c][og * 16 + 0];
    *(float4*)&w[4]  = *(const float4*)&Wt[c][og * 16 + 4];
    *(float4*)&w[8]  = *(const float4*)&Wt[c][og * 16 + 8];
    *(float4*)&w[12] = *(const float4*)&Wt[c][og * 16 + 12];
#pragma unroll
    for (int k = 0; k < 16; ++k) acc[k] += w[k] * xv;
  }

  const int br = m / 3, kind = m % 3;
  if (kind == 2) { // V: fp32 [c][n]
    float* dst = &g_Vf[br][b][0][0] + n;
#pragma unroll
    for (int k = 0; k < 16; ++k) dst[(size_t)(og * 16 + k) * NN] = acc[k];
  } else { // Q/K: bf16 hi/lo, transposed [n][c]
    unsigned short hi[16], lo[16];
#pragma unroll
    for (int k = 0; k < 16; ++k) split_bf(acc[k], hi[k], lo[k]);
    unsigned short* dh = (kind == 0) ? &g_Qh[br][b][n][og * 16] : &g_Kh[br][b][n][og * 16];
    unsigned short* dl = (kind == 0) ? &g_Ql[br][b][n][og * 16] : &g_Kl[br][b][n][og * 16];
    *(uint4*)dh       = *(const uint4*)&hi[0];
    *(uint4*)(dh + 8) = *(const uint4*)&hi[8];
    *(uint4*)dl       = *(const uint4*)&lo[0];
    *(uint4*)(dl + 8) = *(const uint4*)&lo[8];
  }
}

// ---------------------------------------------------------------------------
// Kernel 2: pass 1 — Z[i] = sum_j exp(S[i,j]), S = Q^T K via bf16 hi/lo MFMA.
// grid 512 (bid&7 = image -> XCD pin). Block: 64 i-rows, 4 waves in 2x2
// (wi: 32 i, wj: 32 j of each 64-j tile). Q-frags static in regs; K-tiles
// double-buffered in swizzled LDS with register prefetch.
// ---------------------------------------------------------------------------
__global__ __launch_bounds__(256) void pass1_kernel() {
  __shared__ unsigned short ks_h[2][64 * 64]; // [buf], 64 j-rows x 64 c, swizzled
  __shared__ unsigned short ks_l[2][64 * 64];
  __shared__ float zbuf[2][64];

  const int tid = threadIdx.x;
  const int bid = blockIdx.x;
  const int img = bid & 7;
  const int br = img >> 2, b = img & 3;
  const int i0 = (bid >> 3) << 6;

  const int lane = tid & 63, w = tid >> 6;
  const int wi = w >> 1, wj = w & 1;
  const int lm = lane & 15, q = lane >> 4;

  const unsigned short* __restrict__ QhB = &g_Qh[br][b][0][0];
  const unsigned short* __restrict__ QlB = &g_Ql[br][b][0][0];
  const unsigned short* __restrict__ KhB = &g_Kh[br][b][0][0];
  const unsigned short* __restrict__ KlB = &g_Kl[br][b][0][0];

  // Static A-frags (Q): [it][cstep][hi/lo]
  bf16x8 qa[2][2][2];
#pragma unroll
  for (int it = 0; it < 2; ++it)
#pragma unroll
    for (int cs = 0; cs < 2; ++cs) {
      size_t off = (size_t)(i0 + wi * 32 + it * 16 + lm) * 64 + cs * 32 + q * 8;
      qa[it][cs][0] = *(const bf16x8*)(QhB + off);
      qa[it][cs][1] = *(const bf16x8*)(QlB + off);
    }

  // Staging geometry: 512 16B chunks per array; thread handles 2.
  const int r0 = tid >> 3, s0 = tid & 7;
  const int r1 = (256 + tid) >> 3, s1 = tid & 7;
  const int la0 = r0 * 128 + ((s0 * 16) ^ ((r0 & 7) << 4));
  const int la1 = r1 * 128 + ((s1 * 16) ^ ((r1 & 7) << 4));
  const size_t g0 = (size_t)r0 * 64 + s0 * 8;
  const size_t g1o = (size_t)r1 * 64 + s1 * 8;

  uint4 ph0, ph1, pl0, pl1;
  // tile 0 -> buf 0
  ph0 = *(const uint4*)(KhB + g0); ph1 = *(const uint4*)(KhB + g1o);
  pl0 = *(const uint4*)(KlB + g0); pl1 = *(const uint4*)(KlB + g1o);
  *(uint4*)((char*)ks_h[0] + la0) = ph0; *(uint4*)((char*)ks_h[0] + la1) = ph1;
  *(uint4*)((char*)ks_l[0] + la0) = pl0; *(uint4*)((char*)ks_l[0] + la1) = pl1;
  // prefetch tile 1
  ph0 = *(const uint4*)(KhB + 4096 + g0); ph1 = *(const uint4*)(KhB + 4096 + g1o);
  pl0 = *(const uint4*)(KlB + 4096 + g0); pl1 = *(const uint4*)(KlB + 4096 + g1o);
  lds_barrier();

  float zacc[2][4];
#pragma unroll
  for (int it = 0; it < 2; ++it)
#pragma unroll
    for (int r = 0; r < 4; ++r) zacc[it][r] = 0.f;

  for (int t = 0; t < 64; ++t) {
    const int cur = t & 1;
    if (t < 63) {
      *(uint4*)((char*)ks_h[cur ^ 1] + la0) = ph0;
      *(uint4*)((char*)ks_h[cur ^ 1] + la1) = ph1;
      *(uint4*)((char*)ks_l[cur ^ 1] + la0) = pl0;
      *(uint4*)((char*)ks_l[cur ^ 1] + la1) = pl1;
      if (t < 62) {
        size_t tb = (size_t)(t + 2) * 4096;
        ph0 = *(const uint4*)(KhB + tb + g0); ph1 = *(const uint4*)(KhB + tb + g1o);
        pl0 = *(const uint4*)(KlB + tb + g0); pl1 = *(const uint4*)(KlB + tb + g1o);
      }
    }

    bf16x8 kb[2][2][2]; // [jt][cstep][hi/lo]
#pragma unroll
    for (int jt = 0; jt < 2; ++jt) {
      int row = wj * 32 + jt * 16 + lm;
      int rb = row * 128, sw = (row & 7) << 4;
#pragma unroll
      for (int cs = 0; cs < 2; ++cs) {
        int byte = rb + ((cs * 64 + q * 16) ^ sw);
        kb[jt][cs][0] = *(const bf16x8*)((const char*)ks_h[cur] + byte);
        kb[jt][cs][1] = *(const bf16x8*)((const char*)ks_l[cur] + byte);
      }
    }

    const f32x4 zf = {0.f, 0.f, 0.f, 0.f};
#pragma unroll
    for (int it = 0; it < 2; ++it)
#pragma unroll
      for (int jt = 0; jt < 2; ++jt) {
        f32x4 s = mfma16(qa[it][0][0], kb[jt][0][0], zf);
        s = mfma16(qa[it][1][0], kb[jt][1][0], s);
        s = mfma16(qa[it][0][0], kb[jt][0][1], s);
        s = mfma16(qa[it][1][0], kb[jt][1][1], s);
        s = mfma16(qa[it][0][1], kb[jt][0][0], s);
        s = mfma16(qa[it][1][1], kb[jt][1][0], s);
        zacc[it][0] += __expf(s[0]);
        zacc[it][1] += __expf(s[1]);
        zacc[it][2] += __expf(s[2]);
        zacc[it][3] += __expf(s[3]);
      }
    lds_barrier();
  }

#pragma unroll
  for (int mm = 1; mm < 16; mm <<= 1)
#pragma unroll
    for (int it = 0; it < 2; ++it)
#pragma unroll
      for (int r = 0; r < 4; ++r) zacc[it][r] += __shfl_xor(zacc[it][r], mm, 64);

  if (lm == 0) {
#pragma unroll
    for (int it = 0; it < 2; ++it)
#pragma unroll
      for (int r = 0; r < 4; ++r)
        zbuf[wj][wi * 32 + it * 16 + q * 4 + r] = zacc[it][r];
  }
  __syncthreads();
  if (tid < 64) g_Z[br][b][i0 + tid] = zbuf[0][tid] + zbuf[1][tid];
}

// ---------------------------------------------------------------------------
// Kernel 3: fold g/Z into V and split into bf16 hi/lo [c][n].
// ---------------------------------------------------------------------------
__global__ __launch_bounds__(256) void scalev_kernel(const float* __restrict__ g1,
                                                     const float* __restrict__ g2) {
  int idx = blockIdx.x * 256 + threadIdx.x; // 2*4*64*1024 float4 chunks
  int i4 = idx & 1023;
  int c  = (idx >> 10) & 63;
  int b  = (idx >> 16) & 3;
  int br = idx >> 18;
  float g = br ? g2[0] : g1[0];
  const float4 z = *(const float4*)&g_Z[br][b][i4 * 4];
  float4 v = *(const float4*)&g_Vf[br][b][c][i4 * 4];
  float vv[4] = {v.x * g / z.x, v.y * g / z.y, v.z * g / z.z, v.w * g / z.w};
  unsigned short h[4], l[4];
#pragma unroll
  for (int r = 0; r < 4; ++r) split_bf(vv[r], h[r], l[r]);
  uint2 uh, ul;
  uh.x = (unsigned)h[0] | ((unsigned)h[1] << 16);
  uh.y = (unsigned)h[2] | ((unsigned)h[3] << 16);
  ul.x = (unsigned)l[0] | ((unsigned)l[1] << 16);
  ul.y = (unsigned)l[2] | ((unsigned)l[3] << 16);
  *(uint2*)&g_Vh[br][b][c][i4 * 4] = uh;
  *(uint2*)&g_Vl[br][b][c][i4 * 4] = ul;
}

// ---------------------------------------------------------------------------
// Kernel 4: pass 2 — O[c,j] = sum_i Vn[c,i] * exp(S[i,j]) via MFMA.
// grid 512 (bid&7 = image). Block owns O[64c x 64j]; 4 waves in 2x2.
// Kt-frags static in regs; Q/V frags loaded direct from global (L2) with
// issue-early reuse of the same registers; P staged via 16 KiB swizzled LDS.
// ---------------------------------------------------------------------------
__global__ __launch_bounds__(256, 2) void pass2_kernel() {
  __shared__ unsigned short pt_h[64 * 64]; // [j][i] swizzled
  __shared__ unsigned short pt_l[64 * 64];

  const int tid = threadIdx.x;
  const int bid = blockIdx.x;
  const int img = bid & 7;
  const int br = img >> 2, b = img & 3;
  const int j0 = (bid >> 3) << 6;

  const int lane = tid & 63, w = tid >> 6;
  const int wi = w >> 1, wj = w & 1; // wi: i-sub(S)/c-sub(PV); wj: j-sub
  const int lm = lane & 15, q = lane >> 4;

  const unsigned short* __restrict__ QhB = &g_Qh[br][b][0][0];
  const unsigned short* __restrict__ QlB = &g_Ql[br][b][0][0];
  const unsigned short* __restrict__ KhB = &g_Kh[br][b][0][0];
  const unsigned short* __restrict__ KlB = &g_Kl[br][b][0][0];
  const unsigned short* __restrict__ VhB = &g_Vh[br][b][0][0];
  const unsigned short* __restrict__ VlB = &g_Vl[br][b][0][0];

  // Static B-frags (Kt) for this block's j-columns: [jt][cstep][hi/lo]
  bf16x8 kb[2][2][2];
#pragma unroll
  for (int jt = 0; jt < 2; ++jt)
#pragma unroll
    for (int cs = 0; cs < 2; ++cs) {
      size_t off = (size_t)(j0 + wj * 32 + jt * 16 + lm) * 64 + cs * 32 + q * 8;
      kb[jt][cs][0] = *(const bf16x8*)(KhB + off);
      kb[jt][cs][1] = *(const bf16x8*)(KlB + off);
    }

  bf16x8 qa[2][2][2]; // [it][cstep][hi/lo]
  bf16x8 va[2][2][2]; // [ct][kstep][hi/lo]
  auto loadQ = [&](int ib) {
#pragma unroll
    for (int it = 0; it < 2; ++it)
#pragma unroll
      for (int cs = 0; cs < 2; ++cs) {
        size_t off = (size_t)(ib + wi * 32 + it * 16 + lm) * 64 + cs * 32 + q * 8;
        qa[it][cs][0] = *(const bf16x8*)(QhB + off);
        qa[it][cs][1] = *(const bf16x8*)(QlB + off);
      }
  };
  auto loadV = [&](int ib) {
#pragma unroll
    for (int ct = 0; ct < 2; ++ct)
#pragma unroll
      for (int ks = 0; ks < 2; ++ks) {
        size_t off = (size_t)(wi * 32 + ct * 16 + lm) * NN + ib + ks * 32 + q * 8;
        va[ct][ks][0] = *(const bf16x8*)(VhB + off);
        va[ct][ks][1] = *(const bf16x8*)(VlB + off);
      }
  };
  loadQ(0);
  loadV(0);

  f32x4 oacc[2][2];
#pragma unroll
  for (int ct = 0; ct < 2; ++ct)
#pragma unroll
    for (int jt = 0; jt < 2; ++jt) oacc[ct][jt] = (f32x4){0.f, 0.f, 0.f, 0.f};

  for (int t = 0; t < 64; ++t) {
    const int i0 = t << 6;
    // ---- S phase ----
    const f32x4 zf = {0.f, 0.f, 0.f, 0.f};
    f32x4 sacc[2][2];
#pragma unroll
    for (int it = 0; it < 2; ++it)
#pragma unroll
      for (int jt = 0; jt < 2; ++jt) {
        f32x4 s = mfma16(qa[it][0][0], kb[jt][0][0], zf);
        s = mfma16(qa[it][1][0], kb[jt][1][0], s);
        s = mfma16(qa[it][0][0], kb[jt][0][1], s);
        s = mfma16(qa[it][1][0], kb[jt][1][1], s);
        s = mfma16(qa[it][0][1], kb[jt][0][0], s);
        s = mfma16(qa[it][1][1], kb[jt][1][0], s);
        sacc[it][jt] = s;
      }
    if (t < 63) loadQ(i0 + 64); // issue-early; waited at next iter's S

    // exp + hi/lo split + pack (into regs, before barrier)
    uint2 wh[2][2], wl[2][2];
#pragma unroll
    for (int it = 0; it < 2; ++it)
#pragma unroll
      for (int jt = 0; jt < 2; ++jt) {
        unsigned short h[4], l[4];
#pragma unroll
        for (int r = 0; r < 4; ++r) {
          float e = __expf(sacc[it][jt][r]);
          split_bf(e, h[r], l[r]);
        }
        wh[it][jt].x = (unsigned)h[0] | ((unsigned)h[1] << 16);
        wh[it][jt].y = (unsigned)h[2] | ((unsigned)h[3] << 16);
        wl[it][jt].x = (unsigned)l[0] | ((unsigned)l[1] << 16);
        wl[it][jt].y = (unsigned)l[2] | ((unsigned)l[3] << 16);
      }

    lds_barrier(); // A: previous PV reads of Pt complete
#pragma unroll
    for (int it = 0; it < 2; ++it)
#pragma unroll
      for (int jt = 0; jt < 2; ++jt) {
        int row = wj * 32 + jt * 16 + lm;
        int byte = row * 128 + (((wi * 64) + it * 32 + q * 8) ^ ((row & 7) << 4));
        *(uint2*)((char*)pt_h + byte) = wh[it][jt];
        *(uint2*)((char*)pt_l + byte) = wl[it][jt];
      }
    lds_barrier(); // B: Pt(t) visible

    // ---- PV phase ----
    bf16x8 pb[2][2][2]; // [jt][kstep][hi/lo]
#pragma unroll
    for (int jt = 0; jt < 2; ++jt) {
      int row = wj * 32 + jt * 16 + lm;
      int rb = row * 128, sw = (row & 7) << 4;
#pragma unroll
      for (int ks = 0; ks < 2; ++ks) {
        int byte = rb + ((ks * 64 + q * 16) ^ sw);
        pb[jt][ks][0] = *(const bf16x8*)((const char*)pt_h + byte);
        pb[jt][ks][1] = *(const bf16x8*)((const char*)pt_l + byte);
      }
    }
#pragma unroll
    for (int ct = 0; ct < 2; ++ct)
#pragma unroll
      for (int jt = 0; jt < 2; ++jt) {
        f32x4 o = oacc[ct][jt];
        o = mfma16(va[ct][0][0], pb[jt][0][0], o); // Vh*Ph k0
        o = mfma16(va[ct][1][0], pb[jt][1][0], o); // Vh*Ph k1
        o = mfma16(va[ct][0][0], pb[jt][0][1], o); // Vh*Pl k0
        o = mfma16(va[ct][1][0], pb[jt][1][1], o); // Vh*Pl k1
        o = mfma16(va[ct][0][1], pb[jt][0][0], o); // Vl*Ph k0
        o = mfma16(va[ct][1][1], pb[jt][1][0], o); // Vl*Ph k1
        oacc[ct][jt] = o;
      }
    if (t < 63) loadV(i0 + 64); // issue-early; waited at next iter's PV
  }

  float* __restrict__ Ob = &g_O[br][b][0][0];
#pragma unroll
  for (int ct = 0; ct < 2; ++ct)
#pragma unroll
    for (int jt = 0; jt < 2; ++jt)
#pragma unroll
      for (int r = 0; r < 4; ++r)
        Ob[(size_t)(wi * 32 + ct * 16 + q * 4 + r) * NN + j0 + wj * 32 + jt * 16 + lm] =
            oacc[ct][jt][r];
}

// ---------------------------------------------------------------------------
// Kernel 5: final 1x1 conv over concat (g1/g2 already folded into V).
// ---------------------------------------------------------------------------
__global__ __launch_bounds__(256) void final_kernel(const float* __restrict__ Wf,
                                                    const float* __restrict__ bf,
                                                    float* __restrict__ out) {
  __shared__ float Wt[128][68];
  __shared__ float bs[64];
  const int tid = threadIdx.x;
#pragma unroll
  for (int k = 0; k < 32; ++k) {
    int t = k * 256 + tid; // t = o*128 + c'
    Wt[t & 127][t >> 7] = Wf[t];
  }
  if (tid < 64) bs[tid] = bf[tid];
  __syncthreads();

  const int b = blockIdx.y;
  const int n = (blockIdx.x << 6) + (tid & 63);
  const int og = tid >> 6;
  const float* __restrict__ Oh = &g_O[0][b][0][0];
  const float* __restrict__ Ol = &g_O[1][b][0][0];

  float acc[16];
#pragma unroll
  for (int k = 0; k < 16; ++k) acc[k] = bs[og * 16 + k];

#pragma unroll 4
  for (int c = 0; c < 64; ++c) {
    float xv = Oh[(size_t)c * NN + n];
    float w[16];
    *(float4*)&w[0]  = *(const float4*)&Wt[c][og * 16 + 0];
    *(float4*)&w[4]  = *(const float4*)&Wt[c][og * 16 + 4];
    *(float4*)&w[8]  = *(const float4*)&Wt[c][og * 16 + 8];
    *(float4*)&w[12] = *(const float4*)&Wt[c][og * 16 + 12];
#pragma unroll
    for (int k = 0; k < 16; ++k) acc[k] += w[k] * xv;
  }
#pragma unroll 4
  for (int c = 0; c < 64; ++c) {
    float xv = Ol[(size_t)c * NN + n];
    float w[16];
    *(float4*)&w[0]  = *(const float4*)&Wt[64 + c][og * 16 + 0];
    *(float4*)&w[4]  = *(const float4*)&Wt[64 + c][og * 16 + 4];
    *(float4*)&w[8]  = *(const float4*)&Wt[64 + c][og * 16 + 8];
    *(float4*)&w[12] = *(const float4*)&Wt[64 + c][og * 16 + 12];
#pragma unroll
    for (int k = 0; k < 16; ++k) acc[k] += w[k] * xv;
  }

  float* op = out + ((size_t)b * CD) * NN + n;
#pragma unroll
  for (int k = 0; k < 16; ++k) op[(size_t)(og * 16 + k) * NN] = acc[k];
}

// ---------------------------------------------------------------------------
extern "C" void kernel_launch(void* const* d_in, const int* in_sizes, int n_in,
                              void* d_out, int out_size, void* d_ws, size_t ws_size,
                              hipStream_t stream) {
  (void)in_sizes; (void)n_in; (void)d_ws; (void)ws_size; (void)out_size;

  ProjArgs pa;
  pa.x = (const float*)d_in[0];
  for (int m = 0; m < 6; ++m) {
    pa.W[m]    = (const float*)d_in[1 + 2 * m];
    pa.bias[m] = (const float*)d_in[2 + 2 * m];
  }
  const float* g1 = (const float*)d_in[13];
  const float* g2 = (const float*)d_in[14];
  const float* Wf = (const float*)d_in[15];
  const float* bf = (const float*)d_in[16];
  float* out = (float*)d_out;

  proj_kernel<<<dim3(64, 4, 6), 256, 0, stream>>>(pa);
  pass1_kernel<<<dim3(512), 256, 0, stream>>>();
  scalev_kernel<<<dim3(2048), 256, 0, stream>>>(g1, g2);
  pass2_kernel<<<dim3(512), 256, 0, stream>>>();
  final_kernel<<<dim3(64, 4), 256, 0, stream>>>(Wf, bf, out);
}